// Round 3
// baseline (9497.259 us; speedup 1.0000x reference)
//
#include <hip/hip_runtime.h>
#include <cstdint>

// ---------------- workspace layout (bytes) ----------------
// Wt   : bf16 [2][4096][2048]  transposed weights (col-major rows of W)   32 MiB
// xbf  : bf16 [256][64][1024]  x converted to bf16                        32 MiB
// hbuf : bf16 [4][2][64][1024] ring buffer of h (slot = t & 3)             1 MiB
// kl   : double accumulator
// arr  : int [2][257] arrival counters
#define WS_WT   0UL
#define WS_XBF  33554432UL
#define WS_HBUF 67108864UL
#define WS_KL   68157440UL
#define WS_ARR  68157504UL

typedef __attribute__((ext_vector_type(8))) short short8;   // 8 x bf16 (4 VGPR)
typedef __attribute__((ext_vector_type(4))) float f32x4;    // MFMA acc
typedef __attribute__((ext_vector_type(2))) unsigned long long ull2; // 16B

__device__ __forceinline__ unsigned short f2bf(float f) {
  unsigned int u = __float_as_uint(f);
  u += 0x7FFFu + ((u >> 16) & 1u);      // RNE
  return (unsigned short)(u >> 16);
}

__device__ __forceinline__ float sigm(float x) { return 1.0f / (1.0f + expf(-x)); }

// ---------------- threefry2x32 (matches jax._src.prng) ----------------
__device__ __forceinline__ void tf_round(uint32_t& x0, uint32_t& x1, int r) {
  x0 += x1; x1 = (x1 << r) | (x1 >> (32 - r)); x1 ^= x0;
}
__device__ __forceinline__ void threefry2x32_dev(uint32_t k0, uint32_t k1,
                                                 uint32_t c0, uint32_t c1,
                                                 uint32_t& o0, uint32_t& o1) {
  uint32_t ks2 = k0 ^ k1 ^ 0x1BD11BDAu;
  uint32_t x0 = c0 + k0, x1 = c1 + k1;
  tf_round(x0,x1,13); tf_round(x0,x1,15); tf_round(x0,x1,26); tf_round(x0,x1,6);
  x0 += k1;  x1 += ks2 + 1u;
  tf_round(x0,x1,17); tf_round(x0,x1,29); tf_round(x0,x1,16); tf_round(x0,x1,24);
  x0 += ks2; x1 += k0 + 2u;
  tf_round(x0,x1,13); tf_round(x0,x1,15); tf_round(x0,x1,26); tf_round(x0,x1,6);
  x0 += k0;  x1 += k1 + 3u;
  tf_round(x0,x1,17); tf_round(x0,x1,29); tf_round(x0,x1,16); tf_round(x0,x1,24);
  x0 += k1;  x1 += ks2 + 4u;
  tf_round(x0,x1,13); tf_round(x0,x1,15); tf_round(x0,x1,26); tf_round(x0,x1,6);
  x0 += ks2; x1 += k0 + 5u;
  o0 = x0; o1 = x1;
}

// XLA ErfInv32 (Giles polynomial, log1p form)
__device__ __forceinline__ float erfinv_f32(float x) {
  float w = -log1pf(-x * x);
  float p;
  if (w < 5.0f) {
    w -= 2.5f;
    p = 2.81022636e-08f;
    p = fmaf(p, w, 3.43273939e-07f);
    p = fmaf(p, w, -3.5233877e-06f);
    p = fmaf(p, w, -4.39150654e-06f);
    p = fmaf(p, w, 0.00021858087f);
    p = fmaf(p, w, -0.00125372503f);
    p = fmaf(p, w, -0.00417768164f);
    p = fmaf(p, w, 0.246640727f);
    p = fmaf(p, w, 1.50140941f);
  } else {
    w = sqrtf(w) - 3.0f;
    p = -0.000200214257f;
    p = fmaf(p, w, 0.000100950558f);
    p = fmaf(p, w, 0.00134934322f);
    p = fmaf(p, w, -0.00367342844f);
    p = fmaf(p, w, 0.00573950773f);
    p = fmaf(p, w, -0.0076224613f);
    p = fmaf(p, w, 0.00943887047f);
    p = fmaf(p, w, 1.00167406f);
    p = fmaf(p, w, 2.83297682f);
  }
  return p * x;
}

// bits -> N(0,1) exactly like jax.random.normal(float32)
__device__ __forceinline__ float bits_to_normal(uint32_t b) {
  float f = __uint_as_float((b >> 9) | 0x3f800000u) - 1.0f;   // [0,1)
  float u = fmaf(f, 2.0f, -0.99999994f);                      // *2 is exact
  u = fmaxf(-0.99999994f, u);
  return 1.41421356f * erfinv_f32(u);
}

// per-element KL contribution: log q(w|mu,sigma) - log p(w)
__device__ __forceinline__ double kl_elem(float w, float eps, float sigma) {
  float logq = -0.91893853320f - logf(sigma) - 0.5f * eps * eps;
  float t1 = w * 2.71828182846f;          // w / sigma1, sigma1 = e^-1
  float lp1 = -1.3052328943f - 0.5f * t1 * t1;   // -.5log2pi +1 +log(.25)
  float t2 = w * 1096.6331584f;           // w / sigma2, sigma2 = e^-7
  float lp2 = 5.7933793944f - 0.5f * t2 * t2;    // -.5log2pi +7 +log(.75)
  float mx = fmaxf(lp1, lp2);
  float logp = mx + log1pf(expf(fminf(lp1, lp2) - mx));
  return (double)logq - (double)logp;
}

// ---------------- kernel 1: sample weights + KL ----------------
__global__ __launch_bounds__(256) void gen_weights(
    const float* __restrict__ mu, const float* __restrict__ rho,
    unsigned short* __restrict__ Wt, double* __restrict__ klsum,
    uint32_t ka0, uint32_t ka1, uint32_t kb0, uint32_t kb1)
{
  const int bid = blockIdx.x;
  const int l = bid >> 12;
  const int rem = bid & 4095;
  const int cb = rem >> 6, kb = rem & 63;
  const int tid = threadIdx.x;
  const int cc = tid >> 2, kg = tid & 3;
  const int col = cb * 64 + cc;
  const uint32_t K0 = l ? kb0 : ka0, K1 = l ? kb1 : ka1;
  const float* muL  = mu  + (size_t)l * 8388608;
  const float* rhoL = rho + (size_t)l * 8388608;
  const int kbase = kb * 16 + kg * 4;

  double kl = 0.0;
  unsigned short wlo[4], whi[4];
#pragma unroll
  for (int u = 0; u < 4; ++u) {
    const int kp = kbase + u;
    const uint32_t i = (uint32_t)(kp * 4096 + col);
    uint32_t r0, r1;
    threefry2x32_dev(K0, K1, i, i + 4194304u, r0, r1);
    {
      const float e = bits_to_normal(r0);
      const size_t off = (size_t)kp * 4096 + col;
      const float sg = log1pf(expf(rhoL[off])) + 1e-5f;
      const float w = fmaf(e, sg, muL[off]);
      kl += kl_elem(w, e, sg);
      wlo[u] = f2bf(w);
    }
    {
      const float e = bits_to_normal(r1);
      const size_t off = (size_t)(kp + 1024) * 4096 + col;
      const float sg = log1pf(expf(rhoL[off])) + 1e-5f;
      const float w = fmaf(e, sg, muL[off]);
      kl += kl_elem(w, e, sg);
      whi[u] = f2bf(w);
    }
  }
  const size_t wbase = ((size_t)(l * 4096 + col)) * 2048 + kbase;
  *(ushort4*)(Wt + wbase)        = make_ushort4(wlo[0], wlo[1], wlo[2], wlo[3]);
  *(ushort4*)(Wt + wbase + 1024) = make_ushort4(whi[0], whi[1], whi[2], whi[3]);

#pragma unroll
  for (int off = 32; off > 0; off >>= 1) kl += __shfl_down(kl, off, 64);
  __shared__ double part[4];
  const int lane = tid & 63, wv = tid >> 6;
  if (lane == 0) part[wv] = kl;
  __syncthreads();
  if (tid == 0) atomicAdd(klsum, part[0] + part[1] + part[2] + part[3]);
}

// ---------------- kernel 2: convert x and h0 to bf16 ----------------
__global__ __launch_bounds__(256) void cvt_inputs(
    const float* __restrict__ x, const float* __restrict__ h0,
    unsigned short* __restrict__ xbf, unsigned short* __restrict__ hbuf)
{
  const int total = 4227072;   // (16777216 + 131072) / 4
  for (int idx = blockIdx.x * 256 + threadIdx.x; idx < total; idx += gridDim.x * 256) {
    if (idx < 4194304) {
      float4 v = ((const float4*)x)[idx];
      ((ushort4*)xbf)[idx] = make_ushort4(f2bf(v.x), f2bf(v.y), f2bf(v.z), f2bf(v.w));
    } else {
      const int j = idx - 4194304;
      float4 v = ((const float4*)h0)[j];
      ((ushort4*)hbuf)[j] = make_ushort4(f2bf(v.x), f2bf(v.y), f2bf(v.z), f2bf(v.w));
    }
  }
}

// ---------------- kernel 3: persistent LSTM recurrence (v2) ----------------
// 256 blocks (128/layer) x 512 threads (8 waves). Block owns 8 h-cols
// (= 32 gate cols i|j|f|o). W slice in REGISTERS (64 x short8/lane).
// LDS: h stage [64][1024] bf16 swizzled (128KB) + gate buf [64][33] f32.
// No acquire fence: h staged via agent-scope relaxed 8B atomic loads.
__global__ __launch_bounds__(512) void lstm_rec(
    const unsigned short* __restrict__ Wt, const unsigned short* __restrict__ xbf,
    unsigned short* __restrict__ hbuf, const float* __restrict__ c0,
    const float* __restrict__ bias, float* __restrict__ outp,
    int* __restrict__ arrive)
{
  extern __shared__ char lds[];
  char* hst = lds;                          // 131072 B: h stage
  float* gb = (float*)(lds + 131072);       // [64][33] f32 gate buffer

  const int tid = threadIdx.x;
  const int lane = tid & 63;
  const int wv = tid >> 6;                  // 0..7
  const int blk = blockIdx.x;
  const int layer = blk >> 7;
  const int bi = blk & 127;
  const int hc0 = bi << 3;

  const int rowg = wv & 3, colg = wv >> 2;
  const int lc = colg * 16 + (lane & 15);   // local gate col 0..31
  const int g = lc >> 3, hcl_b = lc & 7;    // gate id, h-col within block
  const int kof = (lane >> 4) * 8;          // k offset within 32-chunk
  const int row = rowg * 16 + (lane & 15);  // batch row for A fragments

  // ---- W fragments -> registers (once) ----
  short8 B[64];
  {
    const unsigned short* wrow =
        Wt + ((size_t)(layer * 4096 + g * 1024 + hc0 + hcl_b)) * 2048 + kof;
#pragma unroll
    for (int kc = 0; kc < 64; ++kc) B[kc] = *(const short8*)(wrow + kc * 32);
  }

  // ---- per-thread epilogue state (thread owns (er, ehc)) ----
  const int er = tid >> 3, ehc = tid & 7;
  float creg = c0[(size_t)layer * 65536 + (size_t)er * 1024 + hc0 + ehc];
  const float b_i = bias[layer * 4096 + hc0 + ehc];
  const float b_j = bias[layer * 4096 + 1024 + hc0 + ehc];
  const float b_f = bias[layer * 4096 + 2048 + hc0 + ehc];
  const float b_o = bias[layer * 4096 + 3072 + hc0 + ehc];

  // ---- staging assignment: wave w stages rows w*8..w*8+7 ----
  const int sr = wv * 8 + ((lane >> 3) & 7);
  const int ks8 = lane & 7;
  int* arr = arrive + layer * 257;

  const int hrd_base = row * 2048 + kof * 2;
  const int hrd_swz = (row & 7) << 4;
  const int swr_swz = (sr & 7) << 4;

  for (int t = 0; t < 256; ++t) {
    // ---- x half (K 0..1023) from L2-cached xbf ----
    f32x4 acc = {0.f, 0.f, 0.f, 0.f};
    {
      const unsigned short* xa = xbf + ((size_t)t * 64 + row) * 1024 + kof;
#pragma unroll
      for (int kc = 0; kc < 32; ++kc)
        acc = __builtin_amdgcn_mfma_f32_16x16x32_bf16(
            *(const short8*)(xa + kc * 32), B[kc], acc, 0, 0, 0);
    }

    // ---- wait for h_t (relaxed poll, NO fence) ----
    if (t > 0) {
      while (__hip_atomic_load(arr + t, __ATOMIC_RELAXED, __HIP_MEMORY_SCOPE_AGENT) < 128)
        __builtin_amdgcn_s_sleep(2);
      __builtin_amdgcn_sched_barrier(0);
    }

    // ---- stage h_t -> LDS (coherent 8B agent loads, swizzled writes) ----
    {
      const unsigned long long* hs = (const unsigned long long*)
          (hbuf + ((size_t)((t & 3) * 2 + layer) * 64 + sr) * 1024);
      unsigned long long v[32];
#pragma unroll
      for (int i = 0; i < 16; ++i) {
        const int e8 = ks8 * 2 + i * 16;
        v[2 * i]     = __hip_atomic_load(hs + e8,     __ATOMIC_RELAXED, __HIP_MEMORY_SCOPE_AGENT);
        v[2 * i + 1] = __hip_atomic_load(hs + e8 + 1, __ATOMIC_RELAXED, __HIP_MEMORY_SCOPE_AGENT);
      }
#pragma unroll
      for (int i = 0; i < 16; ++i) {
        const int k = ks8 * 8 + i * 64;
        const int byte = (sr * 2048 + 2 * k) ^ swr_swz;
        ull2 vv; vv.x = v[2 * i]; vv.y = v[2 * i + 1];
        *(ull2*)(hst + byte) = vv;
      }
    }
    __syncthreads();   // B1: h staged

    // ---- h half (K 1024..2047) from LDS ----
#pragma unroll
    for (int kc = 0; kc < 32; ++kc) {
      short8 av = *(const short8*)(hst + ((hrd_base + kc * 64) ^ hrd_swz));
      acc = __builtin_amdgcn_mfma_f32_16x16x32_bf16(av, B[32 + kc], acc, 0, 0, 0);
    }

    // ---- gates -> LDS gate buffer ----
    {
      const int rbase = rowg * 16 + (lane >> 4) * 4;
#pragma unroll
      for (int q = 0; q < 4; ++q) gb[(rbase + q) * 33 + lc] = acc[q];
    }
    __syncthreads();   // B2: gates visible

    // ---- epilogue: one output element per thread ----
    {
      const float i_ = gb[er * 33 + ehc] + b_i;
      const float j_ = gb[er * 33 + 8 + ehc] + b_j;
      const float f_ = gb[er * 33 + 16 + ehc] + b_f;
      const float o_ = gb[er * 33 + 24 + ehc] + b_o;
      const float nc = creg * sigm(f_ + 1.0f) + sigm(i_) * tanhf(j_);
      const float nh = tanhf(nc) * sigm(o_);
      creg = nc;
      unsigned short* hw = hbuf + ((size_t)(((t + 1) & 3) * 2 + layer) * 64 + er) * 1024;
      hw[hc0 + ehc] = f2bf(nh);
      if (layer == 1) outp[(size_t)t * 65536 + (size_t)er * 1024 + hc0 + ehc] = nh;
      if (t == 255) {
        outp[16777216 + (size_t)layer * 65536 + (size_t)er * 1024 + hc0 + ehc] = nh;
        outp[16908288 + (size_t)layer * 65536 + (size_t)er * 1024 + hc0 + ehc] = nc;
      }
    }
    __syncthreads();   // B3: stores drained to L2 (per-wave vmcnt0 at barrier)

    if (tid == 0 && t < 255)
      __hip_atomic_fetch_add(arr + t + 1, 1, __ATOMIC_RELEASE, __HIP_MEMORY_SCOPE_AGENT);
  }
}

__global__ void finalize_kl(const double* __restrict__ klsum, float* __restrict__ outp) {
  outp[17039360] = (float)(*klsum);
}

// ---------------- host ----------------
static void host_threefry(uint32_t k0, uint32_t k1, uint32_t c0, uint32_t c1,
                          uint32_t& o0, uint32_t& o1) {
  auto rot = [](uint32_t x, int r) { return (x << r) | (x >> (32 - r)); };
  const int ra[4] = {13, 15, 26, 6}, rb[4] = {17, 29, 16, 24};
  uint32_t ks2 = k0 ^ k1 ^ 0x1BD11BDAu, x0 = c0 + k0, x1 = c1 + k1;
  for (int i = 0; i < 4; ++i) { x0 += x1; x1 = rot(x1, ra[i]); x1 ^= x0; } x0 += k1;  x1 += ks2 + 1u;
  for (int i = 0; i < 4; ++i) { x0 += x1; x1 = rot(x1, rb[i]); x1 ^= x0; } x0 += ks2; x1 += k0 + 2u;
  for (int i = 0; i < 4; ++i) { x0 += x1; x1 = rot(x1, ra[i]); x1 ^= x0; } x0 += k0;  x1 += k1 + 3u;
  for (int i = 0; i < 4; ++i) { x0 += x1; x1 = rot(x1, rb[i]); x1 ^= x0; } x0 += k1;  x1 += ks2 + 4u;
  for (int i = 0; i < 4; ++i) { x0 += x1; x1 = rot(x1, ra[i]); x1 ^= x0; } x0 += ks2; x1 += k0 + 5u;
  o0 = x0; o1 = x1;
}

extern "C" void kernel_launch(void* const* d_in, const int* in_sizes, int n_in,
                              void* d_out, int out_size, void* d_ws, size_t ws_size,
                              hipStream_t stream) {
  const float* x    = (const float*)d_in[0];
  const float* h0   = (const float*)d_in[1];
  const float* c0   = (const float*)d_in[2];
  const float* mu   = (const float*)d_in[3];
  const float* rho  = (const float*)d_in[4];
  const float* bias = (const float*)d_in[5];
  float* outp = (float*)d_out;
  char* ws = (char*)d_ws;

  unsigned short* Wt   = (unsigned short*)(ws + WS_WT);
  unsigned short* xbf  = (unsigned short*)(ws + WS_XBF);
  unsigned short* hbuf = (unsigned short*)(ws + WS_HBUF);
  double* klsum        = (double*)(ws + WS_KL);
  int* arrive          = (int*)(ws + WS_ARR);

  hipMemsetAsync(ws + WS_KL, 0, 4096, stream);

  uint32_t ka0, ka1, kb0, kb1;
  host_threefry(0u, 1u, 0u, 0u, ka0, ka1);
  host_threefry(0u, 1u, 0u, 1u, kb0, kb1);

  gen_weights<<<8192, 256, 0, stream>>>(mu, rho, Wt, klsum, ka0, ka1, kb0, kb1);
  cvt_inputs<<<8192, 256, 0, stream>>>(x, h0, xbf, hbuf);

  const int lds_bytes = 131072 + 64 * 33 * 4;   // 139520
  hipFuncSetAttribute((const void*)lstm_rec,
                      hipFuncAttributeMaxDynamicSharedMemorySize, lds_bytes);
  lstm_rec<<<256, 512, lds_bytes, stream>>>(Wt, xbf, hbuf, c0, bias, outp, arrive);
  finalize_kl<<<1, 1, 0, stream>>>(klsum, outp);
}